// Round 15
// baseline (262.682 us; speedup 1.0000x reference)
//
#include <hip/hip_runtime.h>
#include <hip/hip_bf16.h>
#include <stdint.h>

// Problem dims (fixed by the reference)
#define DM 768
#define DI 1536
#define DSTATE 16
#define RNK 48
#define BB 2
#define LL 1024
#define ML (BB * LL)  // 2048 rows (b*l flattened)

// segmented scan config (r28: 64 segments of 16)
#define NSEG 64
#define SEGL (LL / NSEG)   // 16

// proj split-K config (r18): K=1536 -> 8 chunks of 192, grid 8x16x2=256 blocks
// r29: part ld = 96 (only live cols stored)
#define PROJ_NCHUNK 8
#define PROJ_KC (DI / PROJ_NCHUNK)   // 192
#define PLD 96

typedef unsigned short u16;
typedef __bf16 bf16x8 __attribute__((ext_vector_type(8)));
typedef float f32x4 __attribute__((ext_vector_type(4)));

struct __align__(8) u16x4_t { u16 x, y, z, w; };

__device__ __forceinline__ float b2f(u16 u) {
  union { uint32_t i; float f; } v; v.i = ((uint32_t)u) << 16; return v.f;
}
__device__ __forceinline__ u16 f2b(float f) {
  union { float f; uint32_t i; } v; v.f = f;
  uint32_t r = v.i + 0x7FFFu + ((v.i >> 16) & 1u);  // RNE
  return (u16)(r >> 16);
}
__device__ __forceinline__ float silu_f(float x) { return x / (1.f + __expf(-x)); }
__device__ __forceinline__ float softplus_f(float s) {
  return fmaxf(s, 0.f) + __logf(1.f + __expf(-fabsf(s)));
}
// r26: __builtin_exp2f w/o fast-math = 5-op expansion, slower than __expf.
// r27: l-vectorized scan loads break lane coalescing — keep row-major scalar.
__device__ __forceinline__ u16x4_t cvt4(float4 v) {
  u16x4_t o; o.x = f2b(v.x); o.y = f2b(v.y); o.z = f2b(v.z); o.w = f2b(v.w); return o;
}

// async global->LDS, 16B per lane (rule #21: both sides linear, no swizzle).
__device__ __forceinline__ void gl16(const u16* g, u16* l) {
  __builtin_amdgcn_global_load_lds(
      (const __attribute__((address_space(1))) uint32_t*)g,
      (__attribute__((address_space(3))) uint32_t*)l, 16, 0, 0);
}

// ---------------------------------------------------------------------------
// Fused fp32->bf16 conversion of GEMM operands + small-weight packing.
// wcat (128x1536): rows 0..15=W_B, 16..31=W_C, 32..79=W_dt, 80..127=0
// dtWb (1536x64):  cols 0..47=dtW row, 48..63=0
// ---------------------------------------------------------------------------
#define SEG_X    (ML * DM / 4)
#define SEG_W    (DI * DM / 4)
#define SEG_CAT  (128 * DI / 4)
#define SEG_DTW  (DI * 64 / 4)
__global__ __launch_bounds__(256) void convert_kernel(
    const float4* __restrict__ x, const float4* __restrict__ wis,
    const float4* __restrict__ wig, const float4* __restrict__ wout,
    const float* __restrict__ W_B, const float* __restrict__ W_C,
    const float* __restrict__ W_dt,
    const float* __restrict__ W_B_b, const float* __restrict__ W_C_b,
    const float* __restrict__ W_dt_b,
    const float* __restrict__ dtW, const float* __restrict__ dtW_b,
    u16x4_t* __restrict__ xb, u16x4_t* __restrict__ wisb,
    u16x4_t* __restrict__ wigb, u16x4_t* __restrict__ woutb,
    u16x4_t* __restrict__ wcf, u16x4_t* __restrict__ wcb,
    u16x4_t* __restrict__ dtwf, u16x4_t* __restrict__ dtwb)
{
  int idx = blockIdx.x * 256 + threadIdx.x;
  if (idx < SEG_X) { xb[idx] = cvt4(x[idx]); return; }
  idx -= SEG_X;
  if (idx < SEG_W) { wisb[idx] = cvt4(wis[idx]); return; }
  idx -= SEG_W;
  if (idx < SEG_W) { wigb[idx] = cvt4(wig[idx]); return; }
  idx -= SEG_W;
  if (idx < SEG_W) { woutb[idx] = cvt4(wout[idx]); return; }
  idx -= SEG_W;
  if (idx < 2 * SEG_CAT) {
    int dir = idx / SEG_CAT;
    int rem = idx % SEG_CAT;
    int row = rem / (DI / 4), k4 = rem % (DI / 4);
    const float* src = nullptr;
    if (row < 16)      src = (dir ? W_B_b  : W_B)  + (size_t)row * DI + k4 * 4;
    else if (row < 32) src = (dir ? W_C_b  : W_C)  + (size_t)(row - 16) * DI + k4 * 4;
    else if (row < 80) src = (dir ? W_dt_b : W_dt) + (size_t)(row - 32) * DI + k4 * 4;
    u16x4_t o;
    if (src) o = cvt4(*(const float4*)src);
    else { o.x = 0; o.y = 0; o.z = 0; o.w = 0; }
    (dir ? wcb : wcf)[rem] = o;
    return;
  }
  idx -= 2 * SEG_CAT;
  int dir = idx / SEG_DTW;
  int rem = idx % SEG_DTW;
  int d = rem / 16, r4 = rem % 16;
  const float* Dw = dir ? dtW_b : dtW;
  u16x4_t o;
  if (r4 < 12) o = cvt4(*(const float4*)(Dw + (size_t)d * RNK + r4 * 4));
  else { o.x = 0; o.y = 0; o.z = 0; o.w = 0; }
  (dir ? dtwb : dtwf)[rem] = o;
}

// ---------------------------------------------------------------------------
// In-proj GEMM (r25): 64x128 tile -> grid (24,32)=768 blocks = 3 blocks/CU.
// BK=32 gl16 staging + LDS dbuf (24KB), one barrier per K-step.
// epi 0: bf16 out, dual-B silu via B1/Nsplit.
// ---------------------------------------------------------------------------
__global__ __launch_bounds__(256) void gemm_bt(
    const u16* __restrict__ A, const u16* __restrict__ B0,
    const u16* __restrict__ B1, int Nsplit,
    void* __restrict__ Cout, int M, int N, int K, int ldc, int epi)
{
  __shared__ alignas(16) u16 As[2][64 * 32];
  __shared__ alignas(16) u16 Bs[2][128 * 32];
  const int tid = threadIdx.x;
  const int wave = tid >> 6, lane = tid & 63;
  const int bm = blockIdx.y * 64;
  const int bn = blockIdx.x * 128;

  const u16* Bmat = B0;
  int ncol0 = bn;
  int epi_l = epi;
  if (B1 != nullptr && bn >= Nsplit) { Bmat = B1; ncol0 = bn - Nsplit; epi_l = 1; }

  const int c0 = tid, c1 = tid + 256;
  const u16* gA0 = A + (size_t)(bm + (c0 >> 2)) * K + (c0 & 3) * 8;
  const u16* gB0 = Bmat + (size_t)(ncol0 + (c0 >> 2)) * K + (c0 & 3) * 8;
  const u16* gB1 = Bmat + (size_t)(ncol0 + (c1 >> 2)) * K + (c1 & 3) * 8;

  const int wm = (wave & 1) * 32, wn = (wave >> 1) * 64;
  const int rl = lane & 15, q = lane >> 4;

  f32x4 acc[2][4];
#pragma unroll
  for (int i = 0; i < 2; ++i)
#pragma unroll
    for (int j = 0; j < 4; ++j) acc[i][j] = (f32x4){0.f, 0.f, 0.f, 0.f};

  auto stage = [&](int buf, int k0) {
    gl16(gA0 + k0, &As[buf][c0 * 8]);
    gl16(gB0 + k0, &Bs[buf][c0 * 8]);
    gl16(gB1 + k0, &Bs[buf][c1 * 8]);
  };

  stage(0, 0);
  __syncthreads();                       // tile 0 ready
  int cur = 0;
  for (int k0 = 0; k0 < K; k0 += 32) {
    const bool more = (k0 + 32 < K);
    if (more) stage(cur ^ 1, k0 + 32);   // in flight during this tile's compute

    const bf16x8* AsV = (const bf16x8*)As[cur];
    const bf16x8* BsV = (const bf16x8*)Bs[cur];
    bf16x8 af[2], bfv[4];
#pragma unroll
    for (int s = 0; s < 2; ++s)
      af[s] = AsV[(wm + s * 16 + rl) * 4 + q];
#pragma unroll
    for (int j = 0; j < 4; ++j)
      bfv[j] = BsV[(wn + j * 16 + rl) * 4 + q];
#pragma unroll
    for (int i = 0; i < 2; ++i)
#pragma unroll
      for (int j = 0; j < 4; ++j)
        acc[i][j] = __builtin_amdgcn_mfma_f32_16x16x32_bf16(af[i], bfv[j], acc[i][j], 0, 0, 0);

    if (more) {
      __syncthreads();                   // drains prefetch + protects buf reuse
      cur ^= 1;
    }
  }

  // epilogue: C/D layout col=lane&15, row=(lane>>4)*4+reg
#pragma unroll
  for (int i = 0; i < 2; ++i) {
#pragma unroll
    for (int j = 0; j < 4; ++j) {
#pragma unroll
      for (int r = 0; r < 4; ++r) {
        int row = bm + wm + i * 16 + q * 4 + r;
        int col = bn + wn + j * 16 + rl;
        float v = acc[i][j][r];
        if (epi_l == 1) v = silu_f(v);
        ((u16*)Cout)[(size_t)row * ldc + col] = f2b(v);
      }
    }
  }
}

// ---------------------------------------------------------------------------
// Proj GEMM, split-K (r18): part[dir][kc] = xc[:, kc*192:(kc+1)*192] @
// wcat[:, same]^T. Grid (8,16,2)=256 blocks. Reg-staging pipeline.
// r29: part ld=96 (cols 96..127 of wcat are zero-pad — never stored).
// ---------------------------------------------------------------------------
__global__ __launch_bounds__(256) void gemm_proj_sk(
    const u16* __restrict__ xcf, const u16* __restrict__ xcb,
    const u16* __restrict__ wcf, const u16* __restrict__ wcb,
    float* __restrict__ part)
{
  const int dir = blockIdx.z;
  const u16* A = dir ? xcb : xcf;
  const u16* B = dir ? wcb : wcf;
  const int kc = blockIdx.x;
  const int bm = blockIdx.y * 128;
  const int kbase = kc * PROJ_KC;

  __shared__ alignas(16) u16 As[128 * 32];
  __shared__ alignas(16) u16 Bs[128 * 32];
  const int tid = threadIdx.x;
  const int wave = tid >> 6, lane = tid & 63;
  const int c0 = tid, c1 = tid + 256;
  const u16* gA0 = A + (size_t)(bm + (c0 >> 2)) * DI + kbase + (c0 & 3) * 8;
  const u16* gA1 = A + (size_t)(bm + (c1 >> 2)) * DI + kbase + (c1 & 3) * 8;
  const u16* gB0 = B + (size_t)(c0 >> 2) * DI + kbase + (c0 & 3) * 8;
  const u16* gB1 = B + (size_t)(c1 >> 2) * DI + kbase + (c1 & 3) * 8;
  uint4* lA0 = (uint4*)&As[c0 * 8]; uint4* lA1 = (uint4*)&As[c1 * 8];
  uint4* lB0 = (uint4*)&Bs[c0 * 8]; uint4* lB1 = (uint4*)&Bs[c1 * 8];

  const int wm = (wave & 1) * 64, wn = (wave >> 1) * 64;
  const int rl = lane & 15, q = lane >> 4;

  f32x4 acc[4][4];
#pragma unroll
  for (int i = 0; i < 4; ++i)
#pragma unroll
    for (int j = 0; j < 4; ++j) acc[i][j] = (f32x4){0.f, 0.f, 0.f, 0.f};

  const bf16x8* AsV = (const bf16x8*)As;
  const bf16x8* BsV = (const bf16x8*)Bs;

  uint4 ra0 = *(const uint4*)(gA0);
  uint4 ra1 = *(const uint4*)(gA1);
  uint4 rb0 = *(const uint4*)(gB0);
  uint4 rb1 = *(const uint4*)(gB1);

  for (int k0 = 0; k0 < PROJ_KC; k0 += 32) {
    *lA0 = ra0; *lA1 = ra1; *lB0 = rb0; *lB1 = rb1;
    __syncthreads();
    if (k0 + 32 < PROJ_KC) {
      ra0 = *(const uint4*)(gA0 + k0 + 32);
      ra1 = *(const uint4*)(gA1 + k0 + 32);
      rb0 = *(const uint4*)(gB0 + k0 + 32);
      rb1 = *(const uint4*)(gB1 + k0 + 32);
    }
    bf16x8 af[4], bfv[4];
#pragma unroll
    for (int s = 0; s < 4; ++s) {
      af[s]  = AsV[(wm + s * 16 + rl) * 4 + q];
      bfv[s] = BsV[(wn + s * 16 + rl) * 4 + q];
    }
#pragma unroll
    for (int i = 0; i < 4; ++i)
#pragma unroll
      for (int j = 0; j < 4; ++j)
        acc[i][j] = __builtin_amdgcn_mfma_f32_16x16x32_bf16(af[i], bfv[j], acc[i][j], 0, 0, 0);
    __syncthreads();
  }

  float* pout = part + ((size_t)(dir * PROJ_NCHUNK + kc) * ML + bm) * PLD;
#pragma unroll
  for (int i = 0; i < 4; ++i) {
#pragma unroll
    for (int j = 0; j < 4; ++j) {
#pragma unroll
      for (int r = 0; r < 4; ++r) {
        int row = wm + i * 16 + q * 4 + r;
        int col = wn + j * 16 + rl;
        if (col < PLD)
          pout[(size_t)row * PLD + col] = acc[i][j][r];
      }
    }
  }
}

// ---------------------------------------------------------------------------
// Reduce split-K partials (r29: pf/pb ONLY — dtl reduced inline in
// gemm_delta). cols 0..31, 512 blocks.
// ---------------------------------------------------------------------------
__global__ __launch_bounds__(256) void proj_reduce(
    const float* __restrict__ part,
    float* __restrict__ pf, float* __restrict__ pb)
{
  int idx = blockIdx.x * 256 + threadIdx.x;    // over 2*ML*32
  int col = idx & 31;
  int t = idx >> 5;
  int row = t % ML;
  int dir = t / ML;
  const float* p = part + ((size_t)dir * PROJ_NCHUNK * ML + row) * PLD + col;
  float s = 0.f;
#pragma unroll
  for (int c = 0; c < PROJ_NCHUNK; ++c)
    s += p[(size_t)c * ML * PLD];
  (dir ? pb : pf)[(size_t)row * 32 + col] = s;
}

// ---------------------------------------------------------------------------
// Delta GEMM (r29 = r23's inline-reduce form, ld 96): delta = softplus(
// dtl @ dtW^T + dtb) where dtl is 8-way-summed from part cols 32..95 during
// A-staging (same fp32 kc-order + f2b rounding as the old proj_reduce —
// bitwise identical). K=64 single tile. Grid (12,16,2)=384 blocks.
// ---------------------------------------------------------------------------
__global__ __launch_bounds__(256) void gemm_delta(
    const float* __restrict__ part,
    const u16* __restrict__ dtwf, const u16* __restrict__ dtwb,
    const float* __restrict__ dtb, const float* __restrict__ dtb_b,
    u16* __restrict__ df, u16* __restrict__ db)
{
  const int dir = blockIdx.z;
  const u16* Bw = dir ? dtwb : dtwf;
  const float* eb = dir ? dtb_b : dtb;
  u16* Cout = dir ? db : df;
  const int bm = blockIdx.y * 128;
  const int bn = blockIdx.x * 128;

  __shared__ alignas(16) u16 As[128 * 64];
  __shared__ alignas(16) u16 Bs[128 * 64];
  const int tid = threadIdx.x;
  const int wave = tid >> 6, lane = tid & 63;

  // B staging (async): 1024 16B-slots, 4/thread; slot c: row=c>>3, k8=c&7
#pragma unroll
  for (int i = 0; i < 4; ++i) {
    int c = tid + i * 256;
    gl16(Bw + (size_t)(bn + (c >> 3)) * 64 + (c & 7) * 8, &Bs[c * 8]);
  }
  // A staging with inline 8-way split-K reduce (part cols 32..95, ld 96)
  const float* pb0 = part + (size_t)dir * PROJ_NCHUNK * ML * PLD;
#pragma unroll
  for (int i = 0; i < 4; ++i) {
    int c = tid + i * 256;
    int row = c >> 3, kcol = (c & 7) * 8;
    const float* p = pb0 + ((size_t)(bm + row)) * PLD + 32 + kcol;
    float4 s0 = {0.f, 0.f, 0.f, 0.f}, s1 = {0.f, 0.f, 0.f, 0.f};
#pragma unroll
    for (int kc = 0; kc < PROJ_NCHUNK; ++kc) {
      const float* pk = p + (size_t)kc * ML * PLD;
      float4 v0 = *(const float4*)pk;
      float4 v1 = *(const float4*)(pk + 4);
      s0.x += v0.x; s0.y += v0.y; s0.z += v0.z; s0.w += v0.w;
      s1.x += v1.x; s1.y += v1.y; s1.z += v1.z; s1.w += v1.w;
    }
    u16 o[8] = {f2b(s0.x), f2b(s0.y), f2b(s0.z), f2b(s0.w),
                f2b(s1.x), f2b(s1.y), f2b(s1.z), f2b(s1.w)};
    *(uint4*)&As[c * 8] = *(const uint4*)o;
  }
  __syncthreads();

  const int wm = (wave & 1) * 64, wn = (wave >> 1) * 64;
  const int rl = lane & 15, q = lane >> 4;

  f32x4 acc[4][4];
#pragma unroll
  for (int i = 0; i < 4; ++i)
#pragma unroll
    for (int j = 0; j < 4; ++j) acc[i][j] = (f32x4){0.f, 0.f, 0.f, 0.f};

#pragma unroll
  for (int kk = 0; kk < 2; ++kk) {
    bf16x8 af[4], bfv[4];
#pragma unroll
    for (int s = 0; s < 4; ++s) {
      af[s]  = *(const bf16x8*)&As[(wm + s * 16 + rl) * 64 + kk * 32 + q * 8];
      bfv[s] = *(const bf16x8*)&Bs[(wn + s * 16 + rl) * 64 + kk * 32 + q * 8];
    }
#pragma unroll
    for (int i = 0; i < 4; ++i)
#pragma unroll
      for (int j = 0; j < 4; ++j)
        acc[i][j] = __builtin_amdgcn_mfma_f32_16x16x32_bf16(af[i], bfv[j], acc[i][j], 0, 0, 0);
  }

#pragma unroll
  for (int i = 0; i < 4; ++i) {
#pragma unroll
    for (int j = 0; j < 4; ++j) {
#pragma unroll
      for (int r = 0; r < 4; ++r) {
        int row = bm + wm + i * 16 + q * 4 + r;
        int col = bn + wn + j * 16 + rl;
        Cout[(size_t)row * DI + col] = f2b(softplus_f(acc[i][j][r] + eb[col]));
      }
    }
  }
}

// ---------------------------------------------------------------------------
// Out-proj GEMM, 64x64 tile / K-tile 64 (validated r15): 384 blocks.
// ---------------------------------------------------------------------------
__global__ __launch_bounds__(256) void gemm_out64(
    const u16* __restrict__ A, const u16* __restrict__ Bw,
    float* __restrict__ out)
{
  __shared__ alignas(16) u16 As[64 * 72];
  __shared__ alignas(16) u16 Bs[64 * 72];
  const int tid = threadIdx.x;
  const int wave = tid >> 6, lane = tid & 63;
  const int bm = blockIdx.y * 64;
  const int bn = blockIdx.x * 64;

  const int c0 = tid, c1 = tid + 256;
  const u16* gA0 = A + (size_t)(bm + (c0 >> 3)) * DI + (c0 & 7) * 8;
  const u16* gA1 = A + (size_t)(bm + (c1 >> 3)) * DI + (c1 & 7) * 8;
  const u16* gB0 = Bw + (size_t)(bn + (c0 >> 3)) * DI + (c0 & 7) * 8;
  const u16* gB1 = Bw + (size_t)(bn + (c1 >> 3)) * DI + (c1 & 7) * 8;
  uint4* lA0 = (uint4*)&As[(c0 >> 3) * 72 + (c0 & 7) * 8];
  uint4* lA1 = (uint4*)&As[(c1 >> 3) * 72 + (c1 & 7) * 8];
  uint4* lB0 = (uint4*)&Bs[(c0 >> 3) * 72 + (c0 & 7) * 8];
  uint4* lB1 = (uint4*)&Bs[(c1 >> 3) * 72 + (c1 & 7) * 8];

  const int rl = lane & 15, q = lane >> 4;

  f32x4 acc[4];
#pragma unroll
  for (int s = 0; s < 4; ++s) acc[s] = (f32x4){0.f, 0.f, 0.f, 0.f};

  uint4 ra0 = *(const uint4*)gA0, ra1 = *(const uint4*)gA1;
  uint4 rb0 = *(const uint4*)gB0, rb1 = *(const uint4*)gB1;

  for (int k0 = 0; k0 < DI; k0 += 64) {
    *lA0 = ra0; *lA1 = ra1; *lB0 = rb0; *lB1 = rb1;
    __syncthreads();
    if (k0 + 64 < DI) {
      ra0 = *(const uint4*)(gA0 + k0 + 64);
      ra1 = *(const uint4*)(gA1 + k0 + 64);
      rb0 = *(const uint4*)(gB0 + k0 + 64);
      rb1 = *(const uint4*)(gB1 + k0 + 64);
    }
    bf16x8 bf[2], af;
#pragma unroll
    for (int c = 0; c < 2; ++c)
      bf[c] = *(const bf16x8*)&Bs[(wave * 16 + rl) * 72 + c * 32 + q * 8];
#pragma unroll
    for (int s = 0; s < 4; ++s) {
#pragma unroll
      for (int c = 0; c < 2; ++c) {
        af = *(const bf16x8*)&As[(s * 16 + rl) * 72 + c * 32 + q * 8];
        acc[s] = __builtin_amdgcn_mfma_f32_16x16x32_bf16(af, bf[c], acc[s], 0, 0, 0);
      }
    }
    __syncthreads();
  }

#pragma unroll
  for (int s = 0; s < 4; ++s) {
#pragma unroll
    for (int r = 0; r < 4; ++r) {
      int row = bm + s * 16 + q * 4 + r;
      int col = bn + wave * 16 + rl;
      out[(size_t)row * DM + col] = acc[s][r];
    }
  }
}

// ---------------------------------------------------------------------------
// Causal depthwise conv (K=4, fp32 weights) + SiLU, fwd + reversed.
// ---------------------------------------------------------------------------
__global__ void conv_kernel(
    const u16* __restrict__ xsg,
    const float* __restrict__ cw, const float* __restrict__ cb,
    const float* __restrict__ cwb, const float* __restrict__ cbb,
    u16* __restrict__ xc, u16* __restrict__ xcb)
{
  int idx = blockIdx.x * 256 + threadIdx.x;      // over ML*DI
  int d = idx % DI;
  int row = idx / DI;
  int l = row % LL, b = row / LL;
  const u16* base = xsg + (size_t)b * LL * 3072 + d;

  float4 wf = *(const float4*)(cw + d * 4);
  float4 wb = *(const float4*)(cwb + d * 4);
  float wfk[4] = {wf.x, wf.y, wf.z, wf.w};
  float wbk[4] = {wb.x, wb.y, wb.z, wb.w};

  float accf = cb[d];
  float accb = cbb[d];
#pragma unroll
  for (int k = 0; k < 4; ++k) {
    int ls = l - 3 + k;
    if (ls >= 0) {
      accf += wfk[k] * b2f(base[(size_t)ls * 3072]);
      accb += wbk[k] * b2f(base[(size_t)(LL - 1 - ls) * 3072]);
    }
  }
  xc[idx]  = f2b(silu_f(accf));
  xcb[idx] = f2b(silu_f(accb));
}

// ---------------------------------------------------------------------------
// Segmented scan, phase A: per (dir,b,seg,d) compute Sdelta and local
// end-state h_local[16] (h_in=0). SEGL=16, 1536+... blocks.
// ---------------------------------------------------------------------------
__global__ __launch_bounds__(256) void scan_sum(
    const u16* __restrict__ df, const u16* __restrict__ db,
    const u16* __restrict__ xcf, const u16* __restrict__ xcb,
    const float* __restrict__ pf, const float* __restrict__ pb,
    const float* __restrict__ A_log, const float* __restrict__ A_log_b,
    float* __restrict__ sdl, float* __restrict__ bs)
{
  const int dir = blockIdx.z / NSEG, seg = blockIdx.z % NSEG;
  const u16* delta = dir ? db : df;
  const u16* xc = dir ? xcb : xcf;
  const float* proj = dir ? pb : pf;
  const float* Al = dir ? A_log_b : A_log;
  const int b = blockIdx.y;
  const int d = blockIdx.x * 256 + threadIdx.x;
  const int l0 = seg * SEGL;

  __shared__ float Bsh[SEGL][16];
  for (int i = threadIdx.x; i < SEGL * 16; i += 256) {
    int l = i >> 4, n = i & 15;
    Bsh[l][n] = proj[((size_t)b * LL + l0 + l) * 32 + n];
  }
  __syncthreads();

  float An[16];
#pragma unroll
  for (int n = 0; n < 16; ++n) An[n] = -__expf(Al[d * 16 + n]);

  float h[16];
#pragma unroll
  for (int n = 0; n < 16; ++n) h[n] = 0.f;
  float S = 0.f;

  const u16* dbase = delta + ((size_t)b * LL + l0) * DI + d;
  const u16* xbase = xc + ((size_t)b * LL + l0) * DI + d;

  for (int g = 0; g < SEGL; g += 4) {
    float dl4[4], dx4[4];
#pragma unroll
    for (int j = 0; j < 4; ++j) {
      float dv = b2f(dbase[(size_t)(g + j) * DI]);
      float xv = b2f(xbase[(size_t)(g + j) * DI]);
      dl4[j] = dv; dx4[j] = dv * xv;
    }
#pragma unroll
    for (int j = 0; j < 4; ++j) {
      S += dl4[j];
#pragma unroll
      for (int n = 0; n < 16; ++n)
        h[n] = __expf(dl4[j] * An[n]) * h[n] + dx4[j] * Bsh[g + j][n];
    }
  }

  size_t base = (((size_t)dir * BB + b) * NSEG + seg) * DI + d;
  sdl[base] = S;
#pragma unroll
  for (int n = 0; n < 16; ++n) bs[base * 16 + n] = h[n];
}

// ---------------------------------------------------------------------------
// Phase B: compose segment summaries into carry-ins (bs overwritten).
// ---------------------------------------------------------------------------
__global__ __launch_bounds__(256) void scan_carry(
    const float* __restrict__ A_log, const float* __restrict__ A_log_b,
    const float* __restrict__ sdl, float* __restrict__ bs)
{
  int idx = blockIdx.x * 256 + threadIdx.x;   // over 2*BB*DI*16
  int n = idx & 15;
  int t = idx >> 4;
  int d = t % DI;
  int b = (t / DI) % BB;
  int dir = t / (DI * BB);
  const float* Al = dir ? A_log_b : A_log;
  float An = -__expf(Al[d * 16 + n]);
  float h = 0.f;
  for (int s = 0; s < NSEG; ++s) {
    size_t base = (((size_t)dir * BB + b) * NSEG + s) * DI + d;
    float S = sdl[base];
    float bv = bs[base * 16 + n];
    bs[base * 16 + n] = h;
    h = __expf(S * An) * h + bv;
  }
}

// ---------------------------------------------------------------------------
// Phase C + combine, 512 threads (r24/r28): waves 0-3 dir0 seg s, waves 4-7
// dir1 seg NSEG-1-s, 16-step chain, 768 blocks = 3/CU, LDS 20KB.
// xsg gate col already holds silu(z) (r20).
// ---------------------------------------------------------------------------
__global__ __launch_bounds__(512) void scan_apply2(
    const u16* __restrict__ df, const u16* __restrict__ db,
    const u16* __restrict__ xcf, const u16* __restrict__ xcb,
    const float* __restrict__ pf, const float* __restrict__ pb,
    const float* __restrict__ A_log, const float* __restrict__ A_log_b,
    const float* __restrict__ Dp, const float* __restrict__ Dp_b,
    const float* __restrict__ bs, const u16* __restrict__ xsg,
    u16* __restrict__ yc)
{
  const int s = blockIdx.z;                  // fwd segment index
  const int b = blockIdx.y;
  const int tid = threadIdx.x;
  const int half = tid >> 8;                 // 0: dir0, 1: dir1 (wave-uniform)
  const int td = tid & 255;
  const int d = blockIdx.x * 256 + td;

  __shared__ float BCsh[2][SEGL][32];        // per-half [l][0:16)=B,[16:32)=C
  __shared__ u16 ysh[2][SEGL][256];          // per-half y rows (local d-chunk)

  const int seg = half ? (NSEG - 1 - s) : s; // this half's segment (own axis)
  const int l0 = seg * SEGL;
  const float* proj = half ? pb : pf;
  const float* Al   = half ? A_log_b : A_log;
  const float* Dpp  = half ? Dp_b : Dp;
  const u16* delta  = half ? db : df;
  const u16* xc     = half ? xcb : xcf;

  for (int i = td; i < SEGL * 32; i += 256) {
    int l = i >> 5, j = i & 31;
    BCsh[half][l][j] = proj[((size_t)b * LL + l0 + l) * 32 + j];
  }
  __syncthreads();

  float An[16];
#pragma unroll
  for (int n = 0; n < 16; ++n) An[n] = -__expf(Al[d * 16 + n]);
  const float Dv = Dpp[d];

  float h[16];
  size_t cbase = (((size_t)half * BB + b) * NSEG + seg) * DI + d;
#pragma unroll
  for (int n = 0; n < 16; ++n) h[n] = bs[cbase * 16 + n];

  const u16* dbase = delta + ((size_t)b * LL + l0) * DI + d;
  const u16* xbase = xc + ((size_t)b * LL + l0) * DI + d;

  for (int g = 0; g < SEGL; g += 4) {
    float dl4[4], xv4[4];
#pragma unroll
    for (int j = 0; j < 4; ++j) {
      dl4[j] = b2f(dbase[(size_t)(g + j) * DI]);
      xv4[j] = b2f(xbase[(size_t)(g + j) * DI]);
    }
#pragma unroll
    for (int j = 0; j < 4; ++j) {
      float dx = dl4[j] * xv4[j];
      float yv = 0.f;
#pragma unroll
      for (int n = 0; n < 16; ++n) {
        h[n] = __expf(dl4[j] * An[n]) * h[n] + dx * BCsh[half][g + j][n];
        yv += h[n] * BCsh[half][g + j][16 + n];
      }
      ysh[half][g + j][td] = f2b(yv + Dv * xv4[j]);
    }
  }
  __syncthreads();

  // combine: fwd row l = s*SEGL + lrow; y_b at dir1 local row SEGL-1-lrow
  for (int i = tid; i < SEGL * 256; i += 512) {
    int lrow = i >> 8, dd = i & 255;
    int l = s * SEGL + lrow;
    int dg = blockIdx.x * 256 + dd;
    float gate = b2f(xsg[((size_t)b * LL + l) * 3072 + DI + dg]);  // silu(z)
    float out = 0.5f * (b2f(ysh[0][lrow][dd]) +
                        b2f(ysh[1][SEGL - 1 - lrow][dd])) * gate;
    yc[((size_t)b * LL + l) * DI + dg] = f2b(out);
  }
}

// ---------------------------------------------------------------------------
extern "C" void kernel_launch(void* const* d_in, const int* in_sizes, int n_in,
                              void* d_out, int out_size, void* d_ws, size_t ws_size,
                              hipStream_t stream)
{
  const float* x       = (const float*)d_in[0];
  const float* Wis     = (const float*)d_in[1];
  const float* Wig     = (const float*)d_in[2];
  const float* conv_w  = (const float*)d_in[3];
  const float* conv_b  = (const float*)d_in[4];
  const float* conv_wb = (const float*)d_in[5];
  const float* conv_bb = (const float*)d_in[6];
  const float* W_dt    = (const float*)d_in[7];
  const float* W_B     = (const float*)d_in[8];
  const float* W_C     = (const float*)d_in[9];
  const float* dtW     = (const float*)d_in[10];
  const float* dtb     = (const float*)d_in[11];
  const float* A_log   = (const float*)d_in[12];
  const float* Dp      = (const float*)d_in[13];
  const float* W_dt_b  = (const float*)d_in[14];
  const float* W_B_b   = (const float*)d_in[15];
  const float* W_C_b   = (const float*)d_in[16];
  const float* dtW_b   = (const float*)d_in[17];
  const float* dtb_b   = (const float*)d_in[18];
  const float* A_log_b = (const float*)d_in[19];
  const float* Dp_b    = (const float*)d_in[20];
  const float* W_out   = (const float*)d_in[21];

  char* ws = (char*)d_ws;
  size_t off = 0;
  auto alloc = [&](size_t bytes) -> char* {
    char* p = ws + off; off += (bytes + 255) & ~(size_t)255; return p;
  };
  u16*   xb    = (u16*)alloc((size_t)ML * DM * 2);
  u16*   wisb  = (u16*)alloc((size_t)DI * DM * 2);
  u16*   wigb  = (u16*)alloc((size_t)DI * DM * 2);
  u16*   woutb = (u16*)alloc((size_t)DM * DI * 2);
  u16*   xsg = (u16*)alloc((size_t)ML * 3072 * 2);     // [xs | silu(z)]
  u16*   xc  = (u16*)alloc((size_t)ML * DI * 2);
  u16*   xcb = (u16*)alloc((size_t)ML * DI * 2);       // reversed space
  u16*   wcf = (u16*)alloc((size_t)128 * DI * 2);      // [B|C|W_dt|0]
  u16*   wcb = (u16*)alloc((size_t)128 * DI * 2);
  u16*   dtwf = (u16*)alloc((size_t)DI * 64 * 2);      // dtW bf16 K-padded
  u16*   dtwb = (u16*)alloc((size_t)DI * 64 * 2);
  float* pf  = (float*)alloc((size_t)ML * 32 * 4);     // [B|C] fp32, ld 32
  float* pb  = (float*)alloc((size_t)ML * 32 * 4);
  u16*   df  = (u16*)alloc((size_t)ML * DI * 2);       // delta bf16 [m][DI]
  u16*   db  = (u16*)alloc((size_t)ML * DI * 2);
  u16*   yc  = (u16*)alloc((size_t)ML * DI * 2);       // combined y
  float* sdl = (float*)alloc((size_t)2 * BB * NSEG * DI * 4);
  float* bs  = (float*)alloc((size_t)2 * BB * NSEG * DI * 16 * 4);   // 25MB
  float* part = (float*)alloc((size_t)2 * PROJ_NCHUNK * ML * PLD * 4); // 12.6MB

  // 1. fp32->bf16 conversion + weight packing (wcat, dtWb)
  const int conv_total = SEG_X + 3 * SEG_W + 2 * SEG_CAT + 2 * SEG_DTW;
  convert_kernel<<<(conv_total + 255) / 256, 256, 0, stream>>>(
      (const float4*)x, (const float4*)Wis, (const float4*)Wig, (const float4*)W_out,
      W_B, W_C, W_dt, W_B_b, W_C_b, W_dt_b, dtW, dtW_b,
      (u16x4_t*)xb, (u16x4_t*)wisb, (u16x4_t*)wigb, (u16x4_t*)woutb,
      (u16x4_t*)wcf, (u16x4_t*)wcb, (u16x4_t*)dtwf, (u16x4_t*)dtwb);

  // 2. in-proj: [xs | silu(z)] = x @ [Wis; Wig]^T  (64x128 tile, 768 blocks)
  gemm_bt<<<dim3(3072 / 128, ML / 64, 1), 256, 0, stream>>>(
      xb, wisb, wigb, DI, xsg, ML, 3072, DM, 3072, 0);

  // 3. causal conv + silu (fwd + reversed)
  conv_kernel<<<(ML * DI) / 256, 256, 0, stream>>>(
      xsg, conv_w, conv_b, conv_wb, conv_bb, xc, xcb);

  // 4. proj GEMM, split-K (256 blocks, ld 96) + reduce (pf/pb only)
  gemm_proj_sk<<<dim3(PROJ_NCHUNK, ML / 128, 2), 256, 0, stream>>>(
      xc, xcb, wcf, wcb, part);
  proj_reduce<<<(2 * ML * 32) / 256, 256, 0, stream>>>(part, pf, pb);

  // 5. delta GEMM w/ inline dtl reduce: softplus(dtl @ dtW^T + dtb)
  gemm_delta<<<dim3(DI / 128, ML / 128, 2), 256, 0, stream>>>(
      part, dtwf, dtwb, dtb, dtb_b, df, db);

  // 6. segmented scan (NSEG=64): summaries -> carries -> apply+combine
  scan_sum<<<dim3(DI / 256, BB, 2 * NSEG), 256, 0, stream>>>(
      df, db, xc, xcb, pf, pb, A_log, A_log_b, sdl, bs);
  scan_carry<<<(2 * BB * DI * 16) / 256, 256, 0, stream>>>(
      A_log, A_log_b, sdl, bs);
  scan_apply2<<<dim3(DI / 256, BB, NSEG), 512, 0, stream>>>(
      df, db, xc, xcb, pf, pb, A_log, A_log_b, Dp, Dp_b, bs, xsg, yc);

  // 7. out-proj: out = yc @ W_out^T, 64x64 tiles (384 blocks), fp32 to d_out
  gemm_out64<<<dim3(DM / 64, ML / 64, 1), 256, 0, stream>>>(
      yc, woutb, (float*)d_out);
}

// Round 16
// 254.606 us; speedup vs baseline: 1.0317x; 1.0317x over previous
//
#include <hip/hip_runtime.h>
#include <hip/hip_bf16.h>
#include <stdint.h>

// Problem dims (fixed by the reference)
#define DM 768
#define DI 1536
#define DSTATE 16
#define RNK 48
#define BB 2
#define LL 1024
#define ML (BB * LL)  // 2048 rows (b*l flattened)

// segmented scan config (r28: 64 segments of 16 — halves serial chain,
// doubles scan grid; scans are latency-bound per r11/r13 counters)
#define NSEG 64
#define SEGL (LL / NSEG)   // 16

// proj split-K config (r18): K=1536 -> 8 chunks of 192, grid 8x16x2=256 blocks
#define PROJ_NCHUNK 8
#define PROJ_KC (DI / PROJ_NCHUNK)   // 192

typedef unsigned short u16;
typedef __bf16 bf16x8 __attribute__((ext_vector_type(8)));
typedef float f32x4 __attribute__((ext_vector_type(4)));

struct __align__(8) u16x4_t { u16 x, y, z, w; };

__device__ __forceinline__ float b2f(u16 u) {
  union { uint32_t i; float f; } v; v.i = ((uint32_t)u) << 16; return v.f;
}
__device__ __forceinline__ u16 f2b(float f) {
  union { float f; uint32_t i; } v; v.f = f;
  uint32_t r = v.i + 0x7FFFu + ((v.i >> 16) & 1u);  // RNE
  return (u16)(r >> 16);
}
__device__ __forceinline__ float silu_f(float x) { return x / (1.f + __expf(-x)); }
__device__ __forceinline__ float softplus_f(float s) {
  return fmaxf(s, 0.f) + __logf(1.f + __expf(-fabsf(s)));
}
// r26: __builtin_exp2f w/o fast-math = 5-op denormal-correct expansion,
// slower than OCML __expf. r27: l-vectorized scan loads break lane
// coalescing (lanes 4KB apart -> 64 lines/wave-load, 1.8x overfetch).
// r29: part ld 96 + inline dtl reduce regressed (alignment + serialized
// re-read on a 1-barrier kernel). Row-major scalar loads + separate
// proj_reduce are the measured optimum.
__device__ __forceinline__ u16x4_t cvt4(float4 v) {
  u16x4_t o; o.x = f2b(v.x); o.y = f2b(v.y); o.z = f2b(v.z); o.w = f2b(v.w); return o;
}

// async global->LDS, 16B per lane. LDS dest is wave-uniform-base + lane*16,
// linear staging layout (rule #21: both sides linear, no swizzle).
__device__ __forceinline__ void gl16(const u16* g, u16* l) {
  __builtin_amdgcn_global_load_lds(
      (const __attribute__((address_space(1))) uint32_t*)g,
      (__attribute__((address_space(3))) uint32_t*)l, 16, 0, 0);
}

// ---------------------------------------------------------------------------
// Fused fp32->bf16 conversion of GEMM operands + small-weight packing.
// wcat (128x1536): rows 0..15=W_B, 16..31=W_C, 32..79=W_dt, 80..127=0
// dtWb (1536x64):  cols 0..47=dtW row, 48..63=0
// ---------------------------------------------------------------------------
#define SEG_X    (ML * DM / 4)
#define SEG_W    (DI * DM / 4)
#define SEG_CAT  (128 * DI / 4)
#define SEG_DTW  (DI * 64 / 4)
__global__ __launch_bounds__(256) void convert_kernel(
    const float4* __restrict__ x, const float4* __restrict__ wis,
    const float4* __restrict__ wig, const float4* __restrict__ wout,
    const float* __restrict__ W_B, const float* __restrict__ W_C,
    const float* __restrict__ W_dt,
    const float* __restrict__ W_B_b, const float* __restrict__ W_C_b,
    const float* __restrict__ W_dt_b,
    const float* __restrict__ dtW, const float* __restrict__ dtW_b,
    u16x4_t* __restrict__ xb, u16x4_t* __restrict__ wisb,
    u16x4_t* __restrict__ wigb, u16x4_t* __restrict__ woutb,
    u16x4_t* __restrict__ wcf, u16x4_t* __restrict__ wcb,
    u16x4_t* __restrict__ dtwf, u16x4_t* __restrict__ dtwb)
{
  int idx = blockIdx.x * 256 + threadIdx.x;
  if (idx < SEG_X) { xb[idx] = cvt4(x[idx]); return; }
  idx -= SEG_X;
  if (idx < SEG_W) { wisb[idx] = cvt4(wis[idx]); return; }
  idx -= SEG_W;
  if (idx < SEG_W) { wigb[idx] = cvt4(wig[idx]); return; }
  idx -= SEG_W;
  if (idx < SEG_W) { woutb[idx] = cvt4(wout[idx]); return; }
  idx -= SEG_W;
  if (idx < 2 * SEG_CAT) {
    int dir = idx / SEG_CAT;
    int rem = idx % SEG_CAT;
    int row = rem / (DI / 4), k4 = rem % (DI / 4);
    const float* src = nullptr;
    if (row < 16)      src = (dir ? W_B_b  : W_B)  + (size_t)row * DI + k4 * 4;
    else if (row < 32) src = (dir ? W_C_b  : W_C)  + (size_t)(row - 16) * DI + k4 * 4;
    else if (row < 80) src = (dir ? W_dt_b : W_dt) + (size_t)(row - 32) * DI + k4 * 4;
    u16x4_t o;
    if (src) o = cvt4(*(const float4*)src);
    else { o.x = 0; o.y = 0; o.z = 0; o.w = 0; }
    (dir ? wcb : wcf)[rem] = o;
    return;
  }
  idx -= 2 * SEG_CAT;
  int dir = idx / SEG_DTW;
  int rem = idx % SEG_DTW;
  int d = rem / 16, r4 = rem % 16;
  const float* Dw = dir ? dtW_b : dtW;
  u16x4_t o;
  if (r4 < 12) o = cvt4(*(const float4*)(Dw + (size_t)d * RNK + r4 * 4));
  else { o.x = 0; o.y = 0; o.z = 0; o.w = 0; }
  (dir ? dtwb : dtwf)[rem] = o;
}

// ---------------------------------------------------------------------------
// In-proj GEMM (r25): 64x128 tile -> grid (24,32)=768 blocks = 3 blocks/CU.
// BK=32 gl16 staging + LDS dbuf (24KB), one barrier per K-step.
// epi 0: bf16 out, dual-B silu via B1/Nsplit.
// ---------------------------------------------------------------------------
__global__ __launch_bounds__(256) void gemm_bt(
    const u16* __restrict__ A, const u16* __restrict__ B0,
    const u16* __restrict__ B1, int Nsplit,
    void* __restrict__ Cout, int M, int N, int K, int ldc, int epi)
{
  __shared__ alignas(16) u16 As[2][64 * 32];
  __shared__ alignas(16) u16 Bs[2][128 * 32];
  const int tid = threadIdx.x;
  const int wave = tid >> 6, lane = tid & 63;
  const int bm = blockIdx.y * 64;
  const int bn = blockIdx.x * 128;

  const u16* Bmat = B0;
  int ncol0 = bn;
  int epi_l = epi;
  if (B1 != nullptr && bn >= Nsplit) { Bmat = B1; ncol0 = bn - Nsplit; epi_l = 1; }

  const int c0 = tid, c1 = tid + 256;
  const u16* gA0 = A + (size_t)(bm + (c0 >> 2)) * K + (c0 & 3) * 8;
  const u16* gB0 = Bmat + (size_t)(ncol0 + (c0 >> 2)) * K + (c0 & 3) * 8;
  const u16* gB1 = Bmat + (size_t)(ncol0 + (c1 >> 2)) * K + (c1 & 3) * 8;

  const int wm = (wave & 1) * 32, wn = (wave >> 1) * 64;
  const int rl = lane & 15, q = lane >> 4;

  f32x4 acc[2][4];
#pragma unroll
  for (int i = 0; i < 2; ++i)
#pragma unroll
    for (int j = 0; j < 4; ++j) acc[i][j] = (f32x4){0.f, 0.f, 0.f, 0.f};

  auto stage = [&](int buf, int k0) {
    gl16(gA0 + k0, &As[buf][c0 * 8]);
    gl16(gB0 + k0, &Bs[buf][c0 * 8]);
    gl16(gB1 + k0, &Bs[buf][c1 * 8]);
  };

  stage(0, 0);
  __syncthreads();                       // tile 0 ready
  int cur = 0;
  for (int k0 = 0; k0 < K; k0 += 32) {
    const bool more = (k0 + 32 < K);
    if (more) stage(cur ^ 1, k0 + 32);   // in flight during this tile's compute

    const bf16x8* AsV = (const bf16x8*)As[cur];
    const bf16x8* BsV = (const bf16x8*)Bs[cur];
    bf16x8 af[2], bfv[4];
#pragma unroll
    for (int s = 0; s < 2; ++s)
      af[s] = AsV[(wm + s * 16 + rl) * 4 + q];
#pragma unroll
    for (int j = 0; j < 4; ++j)
      bfv[j] = BsV[(wn + j * 16 + rl) * 4 + q];
#pragma unroll
    for (int i = 0; i < 2; ++i)
#pragma unroll
      for (int j = 0; j < 4; ++j)
        acc[i][j] = __builtin_amdgcn_mfma_f32_16x16x32_bf16(af[i], bfv[j], acc[i][j], 0, 0, 0);

    if (more) {
      __syncthreads();                   // drains prefetch + protects buf reuse
      cur ^= 1;
    }
  }

  // epilogue: C/D layout col=lane&15, row=(lane>>4)*4+reg
#pragma unroll
  for (int i = 0; i < 2; ++i) {
#pragma unroll
    for (int j = 0; j < 4; ++j) {
#pragma unroll
      for (int r = 0; r < 4; ++r) {
        int row = bm + wm + i * 16 + q * 4 + r;
        int col = bn + wn + j * 16 + rl;
        float v = acc[i][j][r];
        if (epi_l == 1) v = silu_f(v);
        ((u16*)Cout)[(size_t)row * ldc + col] = f2b(v);
      }
    }
  }
}

// ---------------------------------------------------------------------------
// Proj GEMM, split-K (r18): part[dir][kc] = xc[:, kc*192:(kc+1)*192] @
// wcat[:, same]^T. Grid (8,16,2)=256 blocks. Reg-staging pipeline.
// r22: skip dead stores col>=96 (wcat rows 96..127 are zero-pad).
// ---------------------------------------------------------------------------
__global__ __launch_bounds__(256) void gemm_proj_sk(
    const u16* __restrict__ xcf, const u16* __restrict__ xcb,
    const u16* __restrict__ wcf, const u16* __restrict__ wcb,
    float* __restrict__ part)
{
  const int dir = blockIdx.z;
  const u16* A = dir ? xcb : xcf;
  const u16* B = dir ? wcb : wcf;
  const int kc = blockIdx.x;
  const int bm = blockIdx.y * 128;
  const int kbase = kc * PROJ_KC;

  __shared__ alignas(16) u16 As[128 * 32];
  __shared__ alignas(16) u16 Bs[128 * 32];
  const int tid = threadIdx.x;
  const int wave = tid >> 6, lane = tid & 63;
  const int c0 = tid, c1 = tid + 256;
  const u16* gA0 = A + (size_t)(bm + (c0 >> 2)) * DI + kbase + (c0 & 3) * 8;
  const u16* gA1 = A + (size_t)(bm + (c1 >> 2)) * DI + kbase + (c1 & 3) * 8;
  const u16* gB0 = B + (size_t)(c0 >> 2) * DI + kbase + (c0 & 3) * 8;
  const u16* gB1 = B + (size_t)(c1 >> 2) * DI + kbase + (c1 & 3) * 8;
  uint4* lA0 = (uint4*)&As[c0 * 8]; uint4* lA1 = (uint4*)&As[c1 * 8];
  uint4* lB0 = (uint4*)&Bs[c0 * 8]; uint4* lB1 = (uint4*)&Bs[c1 * 8];

  const int wm = (wave & 1) * 64, wn = (wave >> 1) * 64;
  const int rl = lane & 15, q = lane >> 4;

  f32x4 acc[4][4];
#pragma unroll
  for (int i = 0; i < 4; ++i)
#pragma unroll
    for (int j = 0; j < 4; ++j) acc[i][j] = (f32x4){0.f, 0.f, 0.f, 0.f};

  const bf16x8* AsV = (const bf16x8*)As;
  const bf16x8* BsV = (const bf16x8*)Bs;

  uint4 ra0 = *(const uint4*)(gA0);
  uint4 ra1 = *(const uint4*)(gA1);
  uint4 rb0 = *(const uint4*)(gB0);
  uint4 rb1 = *(const uint4*)(gB1);

  for (int k0 = 0; k0 < PROJ_KC; k0 += 32) {
    *lA0 = ra0; *lA1 = ra1; *lB0 = rb0; *lB1 = rb1;
    __syncthreads();
    if (k0 + 32 < PROJ_KC) {
      ra0 = *(const uint4*)(gA0 + k0 + 32);
      ra1 = *(const uint4*)(gA1 + k0 + 32);
      rb0 = *(const uint4*)(gB0 + k0 + 32);
      rb1 = *(const uint4*)(gB1 + k0 + 32);
    }
    bf16x8 af[4], bfv[4];
#pragma unroll
    for (int s = 0; s < 4; ++s) {
      af[s]  = AsV[(wm + s * 16 + rl) * 4 + q];
      bfv[s] = BsV[(wn + s * 16 + rl) * 4 + q];
    }
#pragma unroll
    for (int i = 0; i < 4; ++i)
#pragma unroll
      for (int j = 0; j < 4; ++j)
        acc[i][j] = __builtin_amdgcn_mfma_f32_16x16x32_bf16(af[i], bfv[j], acc[i][j], 0, 0, 0);
    __syncthreads();
  }

  float* pout = part + ((size_t)(dir * PROJ_NCHUNK + kc) * ML + bm) * 128;
#pragma unroll
  for (int i = 0; i < 4; ++i) {
#pragma unroll
    for (int j = 0; j < 4; ++j) {
#pragma unroll
      for (int r = 0; r < 4; ++r) {
        int row = wm + i * 16 + q * 4 + r;
        int col = wn + j * 16 + rl;
        if (col < 96)
          pout[(size_t)row * 128 + col] = acc[i][j][r];
      }
    }
  }
}

// ---------------------------------------------------------------------------
// Reduce split-K partials: cols 0..31 -> pf/pb fp32 (ld 32);
// cols 32..95 -> dtl bf16 (ld 64).
// ---------------------------------------------------------------------------
__global__ __launch_bounds__(256) void proj_reduce(
    const float* __restrict__ part,
    float* __restrict__ pf, float* __restrict__ pb,
    u16* __restrict__ dtlf, u16* __restrict__ dtlb)
{
  int idx = blockIdx.x * 256 + threadIdx.x;    // over 2*ML*96
  int col = idx % 96;
  int t = idx / 96;
  int row = t % ML;
  int dir = t / ML;
  const float* p = part + ((size_t)dir * PROJ_NCHUNK * ML + row) * 128 + col;
  float s = 0.f;
#pragma unroll
  for (int c = 0; c < PROJ_NCHUNK; ++c)
    s += p[(size_t)c * ML * 128];
  if (col < 32) (dir ? pb : pf)[(size_t)row * 32 + col] = s;
  else          (dir ? dtlb : dtlf)[(size_t)row * 64 + (col - 32)] = f2b(s);
}

// ---------------------------------------------------------------------------
// Delta GEMM (specialized, r23): delta = softplus(dtl @ dtW^T + dtb).
// K=64 single staged tile (async gl16), one barrier. Grid (12,16,2)=384.
// Row-major [m][DI] output (scans read it lane-coalesced).
// ---------------------------------------------------------------------------
__global__ __launch_bounds__(256) void gemm_delta(
    const u16* __restrict__ dtlf, const u16* __restrict__ dtlb,
    const u16* __restrict__ dtwf, const u16* __restrict__ dtwb,
    const float* __restrict__ dtb, const float* __restrict__ dtb_b,
    u16* __restrict__ df, u16* __restrict__ db)
{
  const int dir = blockIdx.z;
  const u16* A = dir ? dtlb : dtlf;
  const u16* Bw = dir ? dtwb : dtwf;
  const float* eb = dir ? dtb_b : dtb;
  u16* Cout = dir ? db : df;
  const int bm = blockIdx.y * 128;
  const int bn = blockIdx.x * 128;

  __shared__ alignas(16) u16 As[128 * 64];
  __shared__ alignas(16) u16 Bs[128 * 64];
  const int tid = threadIdx.x;
  const int wave = tid >> 6, lane = tid & 63;

#pragma unroll
  for (int i = 0; i < 4; ++i) {
    int c = tid + i * 256;               // slot: row=c>>3, k8=c&7
    gl16(A  + (size_t)(bm + (c >> 3)) * 64 + (c & 7) * 8, &As[c * 8]);
    gl16(Bw + (size_t)(bn + (c >> 3)) * 64 + (c & 7) * 8, &Bs[c * 8]);
  }
  __syncthreads();

  const int wm = (wave & 1) * 64, wn = (wave >> 1) * 64;
  const int rl = lane & 15, q = lane >> 4;

  f32x4 acc[4][4];
#pragma unroll
  for (int i = 0; i < 4; ++i)
#pragma unroll
    for (int j = 0; j < 4; ++j) acc[i][j] = (f32x4){0.f, 0.f, 0.f, 0.f};

#pragma unroll
  for (int kk = 0; kk < 2; ++kk) {
    bf16x8 af[4], bfv[4];
#pragma unroll
    for (int s = 0; s < 4; ++s) {
      af[s]  = *(const bf16x8*)&As[(wm + s * 16 + rl) * 64 + kk * 32 + q * 8];
      bfv[s] = *(const bf16x8*)&Bs[(wn + s * 16 + rl) * 64 + kk * 32 + q * 8];
    }
#pragma unroll
    for (int i = 0; i < 4; ++i)
#pragma unroll
      for (int j = 0; j < 4; ++j)
        acc[i][j] = __builtin_amdgcn_mfma_f32_16x16x32_bf16(af[i], bfv[j], acc[i][j], 0, 0, 0);
  }

#pragma unroll
  for (int i = 0; i < 4; ++i) {
#pragma unroll
    for (int j = 0; j < 4; ++j) {
#pragma unroll
      for (int r = 0; r < 4; ++r) {
        int row = bm + wm + i * 16 + q * 4 + r;
        int col = bn + wn + j * 16 + rl;
        Cout[(size_t)row * DI + col] = f2b(softplus_f(acc[i][j][r] + eb[col]));
      }
    }
  }
}

// ---------------------------------------------------------------------------
// Out-proj GEMM, 64x64 tile / K-tile 64 (validated r15): 384 blocks.
// ---------------------------------------------------------------------------
__global__ __launch_bounds__(256) void gemm_out64(
    const u16* __restrict__ A, const u16* __restrict__ Bw,
    float* __restrict__ out)
{
  __shared__ alignas(16) u16 As[64 * 72];
  __shared__ alignas(16) u16 Bs[64 * 72];
  const int tid = threadIdx.x;
  const int wave = tid >> 6, lane = tid & 63;
  const int bm = blockIdx.y * 64;
  const int bn = blockIdx.x * 64;

  const int c0 = tid, c1 = tid + 256;
  const u16* gA0 = A + (size_t)(bm + (c0 >> 3)) * DI + (c0 & 7) * 8;
  const u16* gA1 = A + (size_t)(bm + (c1 >> 3)) * DI + (c1 & 7) * 8;
  const u16* gB0 = Bw + (size_t)(bn + (c0 >> 3)) * DI + (c0 & 7) * 8;
  const u16* gB1 = Bw + (size_t)(bn + (c1 >> 3)) * DI + (c1 & 7) * 8;
  uint4* lA0 = (uint4*)&As[(c0 >> 3) * 72 + (c0 & 7) * 8];
  uint4* lA1 = (uint4*)&As[(c1 >> 3) * 72 + (c1 & 7) * 8];
  uint4* lB0 = (uint4*)&Bs[(c0 >> 3) * 72 + (c0 & 7) * 8];
  uint4* lB1 = (uint4*)&Bs[(c1 >> 3) * 72 + (c1 & 7) * 8];

  const int rl = lane & 15, q = lane >> 4;

  f32x4 acc[4];
#pragma unroll
  for (int s = 0; s < 4; ++s) acc[s] = (f32x4){0.f, 0.f, 0.f, 0.f};

  uint4 ra0 = *(const uint4*)gA0, ra1 = *(const uint4*)gA1;
  uint4 rb0 = *(const uint4*)gB0, rb1 = *(const uint4*)gB1;

  for (int k0 = 0; k0 < DI; k0 += 64) {
    *lA0 = ra0; *lA1 = ra1; *lB0 = rb0; *lB1 = rb1;
    __syncthreads();
    if (k0 + 64 < DI) {
      ra0 = *(const uint4*)(gA0 + k0 + 64);
      ra1 = *(const uint4*)(gA1 + k0 + 64);
      rb0 = *(const uint4*)(gB0 + k0 + 64);
      rb1 = *(const uint4*)(gB1 + k0 + 64);
    }
    bf16x8 bf[2], af;
#pragma unroll
    for (int c = 0; c < 2; ++c)
      bf[c] = *(const bf16x8*)&Bs[(wave * 16 + rl) * 72 + c * 32 + q * 8];
#pragma unroll
    for (int s = 0; s < 4; ++s) {
#pragma unroll
      for (int c = 0; c < 2; ++c) {
        af = *(const bf16x8*)&As[(s * 16 + rl) * 72 + c * 32 + q * 8];
        acc[s] = __builtin_amdgcn_mfma_f32_16x16x32_bf16(af, bf[c], acc[s], 0, 0, 0);
      }
    }
    __syncthreads();
  }

#pragma unroll
  for (int s = 0; s < 4; ++s) {
#pragma unroll
    for (int r = 0; r < 4; ++r) {
      int row = bm + s * 16 + q * 4 + r;
      int col = bn + wave * 16 + rl;
      out[(size_t)row * DM + col] = acc[s][r];
    }
  }
}

// ---------------------------------------------------------------------------
// Causal depthwise conv (K=4, fp32 weights) + SiLU, fwd + reversed.
// r12-proven scalar form (lane-coalesced in d).
// ---------------------------------------------------------------------------
__global__ void conv_kernel(
    const u16* __restrict__ xsg,
    const float* __restrict__ cw, const float* __restrict__ cb,
    const float* __restrict__ cwb, const float* __restrict__ cbb,
    u16* __restrict__ xc, u16* __restrict__ xcb)
{
  int idx = blockIdx.x * 256 + threadIdx.x;      // over ML*DI
  int d = idx % DI;
  int row = idx / DI;
  int l = row % LL, b = row / LL;
  const u16* base = xsg + (size_t)b * LL * 3072 + d;

  float4 wf = *(const float4*)(cw + d * 4);
  float4 wb = *(const float4*)(cwb + d * 4);
  float wfk[4] = {wf.x, wf.y, wf.z, wf.w};
  float wbk[4] = {wb.x, wb.y, wb.z, wb.w};

  float accf = cb[d];
  float accb = cbb[d];
#pragma unroll
  for (int k = 0; k < 4; ++k) {
    int ls = l - 3 + k;
    if (ls >= 0) {
      accf += wfk[k] * b2f(base[(size_t)ls * 3072]);
      accb += wbk[k] * b2f(base[(size_t)(LL - 1 - ls) * 3072]);
    }
  }
  xc[idx]  = f2b(silu_f(accf));
  xcb[idx] = f2b(silu_f(accb));
}

// ---------------------------------------------------------------------------
// Segmented scan, phase A: per (dir,b,seg,d) compute Sdelta and local
// end-state h_local[16] (h_in=0). Row-major delta/xc (lane-coalesced).
// r28: SEGL=16, grid z=128 -> 1536 blocks.
// ---------------------------------------------------------------------------
__global__ __launch_bounds__(256) void scan_sum(
    const u16* __restrict__ df, const u16* __restrict__ db,
    const u16* __restrict__ xcf, const u16* __restrict__ xcb,
    const float* __restrict__ pf, const float* __restrict__ pb,
    const float* __restrict__ A_log, const float* __restrict__ A_log_b,
    float* __restrict__ sdl, float* __restrict__ bs)
{
  const int dir = blockIdx.z / NSEG, seg = blockIdx.z % NSEG;
  const u16* delta = dir ? db : df;
  const u16* xc = dir ? xcb : xcf;
  const float* proj = dir ? pb : pf;
  const float* Al = dir ? A_log_b : A_log;
  const int b = blockIdx.y;
  const int d = blockIdx.x * 256 + threadIdx.x;
  const int l0 = seg * SEGL;

  __shared__ float Bsh[SEGL][16];
  for (int i = threadIdx.x; i < SEGL * 16; i += 256) {
    int l = i >> 4, n = i & 15;
    Bsh[l][n] = proj[((size_t)b * LL + l0 + l) * 32 + n];
  }
  __syncthreads();

  float An[16];
#pragma unroll
  for (int n = 0; n < 16; ++n) An[n] = -__expf(Al[d * 16 + n]);

  float h[16];
#pragma unroll
  for (int n = 0; n < 16; ++n) h[n] = 0.f;
  float S = 0.f;

  const u16* dbase = delta + ((size_t)b * LL + l0) * DI + d;
  const u16* xbase = xc + ((size_t)b * LL + l0) * DI + d;

  for (int g = 0; g < SEGL; g += 4) {
    float dl4[4], dx4[4];
#pragma unroll
    for (int j = 0; j < 4; ++j) {
      float dv = b2f(dbase[(size_t)(g + j) * DI]);
      float xv = b2f(xbase[(size_t)(g + j) * DI]);
      dl4[j] = dv; dx4[j] = dv * xv;
    }
#pragma unroll
    for (int j = 0; j < 4; ++j) {
      S += dl4[j];
#pragma unroll
      for (int n = 0; n < 16; ++n)
        h[n] = __expf(dl4[j] * An[n]) * h[n] + dx4[j] * Bsh[g + j][n];
    }
  }

  size_t base = (((size_t)dir * BB + b) * NSEG + seg) * DI + d;
  sdl[base] = S;
#pragma unroll
  for (int n = 0; n < 16; ++n) bs[base * 16 + n] = h[n];
}

// ---------------------------------------------------------------------------
// Phase B: compose segment summaries into carry-ins (bs overwritten).
// r28: 64-segment walk (still a ~4us kernel, off the critical kernels).
// ---------------------------------------------------------------------------
__global__ __launch_bounds__(256) void scan_carry(
    const float* __restrict__ A_log, const float* __restrict__ A_log_b,
    const float* __restrict__ sdl, float* __restrict__ bs)
{
  int idx = blockIdx.x * 256 + threadIdx.x;   // over 2*BB*DI*16
  int n = idx & 15;
  int t = idx >> 4;
  int d = t % DI;
  int b = (t / DI) % BB;
  int dir = t / (DI * BB);
  const float* Al = dir ? A_log_b : A_log;
  float An = -__expf(Al[d * 16 + n]);
  float h = 0.f;
  for (int s = 0; s < NSEG; ++s) {
    size_t base = (((size_t)dir * BB + b) * NSEG + s) * DI + d;
    float S = sdl[base];
    float bv = bs[base * 16 + n];
    bs[base * 16 + n] = h;
    h = __expf(S * An) * h + bv;
  }
}

// ---------------------------------------------------------------------------
// Phase C + combine, 512 threads (r24): waves 0-3 run dir0 seg s, waves 4-7
// run dir1 seg NSEG-1-s concurrently. r28: SEGL=16 -> 16-step chain, grid
// z=64 -> 768 blocks = 3/CU, LDS 20KB. Row-major loads (lane-coalesced).
// xsg gate col already holds silu(z) (r20).
// ---------------------------------------------------------------------------
__global__ __launch_bounds__(512) void scan_apply2(
    const u16* __restrict__ df, const u16* __restrict__ db,
    const u16* __restrict__ xcf, const u16* __restrict__ xcb,
    const float* __restrict__ pf, const float* __restrict__ pb,
    const float* __restrict__ A_log, const float* __restrict__ A_log_b,
    const float* __restrict__ Dp, const float* __restrict__ Dp_b,
    const float* __restrict__ bs, const u16* __restrict__ xsg,
    u16* __restrict__ yc)
{
  const int s = blockIdx.z;                  // fwd segment index
  const int b = blockIdx.y;
  const int tid = threadIdx.x;
  const int half = tid >> 8;                 // 0: dir0, 1: dir1 (wave-uniform)
  const int td = tid & 255;
  const int d = blockIdx.x * 256 + td;

  __shared__ float BCsh[2][SEGL][32];        // per-half [l][0:16)=B,[16:32)=C
  __shared__ u16 ysh[2][SEGL][256];          // per-half y rows (local d-chunk)

  const int seg = half ? (NSEG - 1 - s) : s; // this half's segment (own axis)
  const int l0 = seg * SEGL;
  const float* proj = half ? pb : pf;
  const float* Al   = half ? A_log_b : A_log;
  const float* Dpp  = half ? Dp_b : Dp;
  const u16* delta  = half ? db : df;
  const u16* xc     = half ? xcb : xcf;

  for (int i = td; i < SEGL * 32; i += 256) {
    int l = i >> 5, j = i & 31;
    BCsh[half][l][j] = proj[((size_t)b * LL + l0 + l) * 32 + j];
  }
  __syncthreads();

  float An[16];
#pragma unroll
  for (int n = 0; n < 16; ++n) An[n] = -__expf(Al[d * 16 + n]);
  const float Dv = Dpp[d];

  float h[16];
  size_t cbase = (((size_t)half * BB + b) * NSEG + seg) * DI + d;
#pragma unroll
  for (int n = 0; n < 16; ++n) h[n] = bs[cbase * 16 + n];

  const u16* dbase = delta + ((size_t)b * LL + l0) * DI + d;
  const u16* xbase = xc + ((size_t)b * LL + l0) * DI + d;

  for (int g = 0; g < SEGL; g += 4) {
    float dl4[4], xv4[4];
#pragma unroll
    for (int j = 0; j < 4; ++j) {
      dl4[j] = b2f(dbase[(size_t)(g + j) * DI]);
      xv4[j] = b2f(xbase[(size_t)(g + j) * DI]);
    }
#pragma unroll
    for (int j = 0; j < 4; ++j) {
      float dx = dl4[j] * xv4[j];
      float yv = 0.f;
#pragma unroll
      for (int n = 0; n < 16; ++n) {
        h[n] = __expf(dl4[j] * An[n]) * h[n] + dx * BCsh[half][g + j][n];
        yv += h[n] * BCsh[half][g + j][16 + n];
      }
      ysh[half][g + j][td] = f2b(yv + Dv * xv4[j]);
    }
  }
  __syncthreads();

  // combine: fwd row l = s*SEGL + lrow; y_b at dir1 local row SEGL-1-lrow
  for (int i = tid; i < SEGL * 256; i += 512) {
    int lrow = i >> 8, dd = i & 255;
    int l = s * SEGL + lrow;
    int dg = blockIdx.x * 256 + dd;
    float gate = b2f(xsg[((size_t)b * LL + l) * 3072 + DI + dg]);  // silu(z)
    float out = 0.5f * (b2f(ysh[0][lrow][dd]) +
                        b2f(ysh[1][SEGL - 1 - lrow][dd])) * gate;
    yc[((size_t)b * LL + l) * DI + dg] = f2b(out);
  }
}

// ---------------------------------------------------------------------------
extern "C" void kernel_launch(void* const* d_in, const int* in_sizes, int n_in,
                              void* d_out, int out_size, void* d_ws, size_t ws_size,
                              hipStream_t stream)
{
  const float* x       = (const float*)d_in[0];
  const float* Wis     = (const float*)d_in[1];
  const float* Wig     = (const float*)d_in[2];
  const float* conv_w  = (const float*)d_in[3];
  const float* conv_b  = (const float*)d_in[4];
  const float* conv_wb = (const float*)d_in[5];
  const float* conv_bb = (const float*)d_in[6];
  const float* W_dt    = (const float*)d_in[7];
  const float* W_B     = (const float*)d_in[8];
  const float* W_C     = (const float*)d_in[9];
  const float* dtW     = (const float*)d_in[10];
  const float* dtb     = (const float*)d_in[11];
  const float* A_log   = (const float*)d_in[12];
  const float* Dp      = (const float*)d_in[13];
  const float* W_dt_b  = (const float*)d_in[14];
  const float* W_B_b   = (const float*)d_in[15];
  const float* W_C_b   = (const float*)d_in[16];
  const float* dtW_b   = (const float*)d_in[17];
  const float* dtb_b   = (const float*)d_in[18];
  const float* A_log_b = (const float*)d_in[19];
  const float* Dp_b    = (const float*)d_in[20];
  const float* W_out   = (const float*)d_in[21];

  char* ws = (char*)d_ws;
  size_t off = 0;
  auto alloc = [&](size_t bytes) -> char* {
    char* p = ws + off; off += (bytes + 255) & ~(size_t)255; return p;
  };
  u16*   xb    = (u16*)alloc((size_t)ML * DM * 2);
  u16*   wisb  = (u16*)alloc((size_t)DI * DM * 2);
  u16*   wigb  = (u16*)alloc((size_t)DI * DM * 2);
  u16*   woutb = (u16*)alloc((size_t)DM * DI * 2);
  u16*   xsg = (u16*)alloc((size_t)ML * 3072 * 2);     // [xs | silu(z)]
  u16*   xc  = (u16*)alloc((size_t)ML * DI * 2);
  u16*   xcb = (u16*)alloc((size_t)ML * DI * 2);       // reversed space
  u16*   wcf = (u16*)alloc((size_t)128 * DI * 2);      // [B|C|W_dt|0]
  u16*   wcb = (u16*)alloc((size_t)128 * DI * 2);
  u16*   dtwf = (u16*)alloc((size_t)DI * 64 * 2);      // dtW bf16 K-padded
  u16*   dtwb = (u16*)alloc((size_t)DI * 64 * 2);
  float* pf  = (float*)alloc((size_t)ML * 32 * 4);     // [B|C] fp32, ld 32
  float* pb  = (float*)alloc((size_t)ML * 32 * 4);
  u16*   dtlf = (u16*)alloc((size_t)ML * 64 * 2);      // dt_low bf16, ld 64
  u16*   dtlb = (u16*)alloc((size_t)ML * 64 * 2);
  u16*   df  = (u16*)alloc((size_t)ML * DI * 2);       // delta bf16 [m][DI]
  u16*   db  = (u16*)alloc((size_t)ML * DI * 2);
  u16*   yc  = (u16*)alloc((size_t)ML * DI * 2);       // combined y
  float* sdl = (float*)alloc((size_t)2 * BB * NSEG * DI * 4);
  float* bs  = (float*)alloc((size_t)2 * BB * NSEG * DI * 16 * 4);   // 25MB
  float* part = (float*)alloc((size_t)2 * PROJ_NCHUNK * ML * 128 * 4);  // 16.8MB

  // 1. fp32->bf16 conversion + weight packing (wcat, dtWb)
  const int conv_total = SEG_X + 3 * SEG_W + 2 * SEG_CAT + 2 * SEG_DTW;
  convert_kernel<<<(conv_total + 255) / 256, 256, 0, stream>>>(
      (const float4*)x, (const float4*)Wis, (const float4*)Wig, (const float4*)W_out,
      W_B, W_C, W_dt, W_B_b, W_C_b, W_dt_b, dtW, dtW_b,
      (u16x4_t*)xb, (u16x4_t*)wisb, (u16x4_t*)wigb, (u16x4_t*)woutb,
      (u16x4_t*)wcf, (u16x4_t*)wcb, (u16x4_t*)dtwf, (u16x4_t*)dtwb);

  // 2. in-proj: [xs | silu(z)] = x @ [Wis; Wig]^T  (64x128 tile, 768 blocks)
  gemm_bt<<<dim3(3072 / 128, ML / 64, 1), 256, 0, stream>>>(
      xb, wisb, wigb, DI, xsg, ML, 3072, DM, 3072, 0);

  // 3. causal conv + silu (fwd + reversed)
  conv_kernel<<<(ML * DI) / 256, 256, 0, stream>>>(
      xsg, conv_w, conv_b, conv_wb, conv_bb, xc, xcb);

  // 4. proj GEMM, split-K (256 blocks) + reduce -> pf/pb + dtl
  gemm_proj_sk<<<dim3(PROJ_NCHUNK, ML / 128, 2), 256, 0, stream>>>(
      xc, xcb, wcf, wcb, part);
  proj_reduce<<<(2 * ML * 96) / 256, 256, 0, stream>>>(
      part, pf, pb, dtlf, dtlb);

  // 5. delta GEMM: softplus(dtl @ dtW^T + dtb), single K=64 tile
  gemm_delta<<<dim3(DI / 128, ML / 128, 2), 256, 0, stream>>>(
      dtlf, dtlb, dtwf, dtwb, dtb, dtb_b, df, db);

  // 6. segmented scan (NSEG=64): summaries -> carries -> apply+combine
  scan_sum<<<dim3(DI / 256, BB, 2 * NSEG), 256, 0, stream>>>(
      df, db, xc, xcb, pf, pb, A_log, A_log_b, sdl, bs);
  scan_carry<<<(2 * BB * DI * 16) / 256, 256, 0, stream>>>(
      A_log, A_log_b, sdl, bs);
  scan_apply2<<<dim3(DI / 256, BB, NSEG), 512, 0, stream>>>(
      df, db, xc, xcb, pf, pb, A_log, A_log_b, Dp, Dp_b, bs, xsg, yc);

  // 7. out-proj: out = yc @ W_out^T, 64x64 tiles (384 blocks), fp32 to d_out
  gemm_out64<<<dim3(DM / 64, ML / 64, 1), 256, 0, stream>>>(
      yc, woutb, (float*)d_out);
}